// Round 19
// baseline (207.098 us; speedup 1.0000x reference)
//
#include <hip/hip_runtime.h>
#include <cstdint>

using u64 = unsigned long long;
using u32 = unsigned int;
typedef __attribute__((ext_vector_type(4))) int int4v;
typedef __attribute__((ext_vector_type(16))) int int16v;

// ---------------------------------------------------------------------------
// Prep bodies (called from the fused front kernel).
// ---------------------------------------------------------------------------
struct PrepArgs {
  const float* bng[5]; const float* bnb[5]; const float* bnm[5]; const float* bnv[5];
  float* inv1; float* cc1; float* inv5; float* cc5;
  int* thr[3]; int* flp[3];
  const float* w[4];
  u64* wp[4]; u64* wz[4];
  u32* flags;
  const float* x; float* xpad;
  signed char* bf2x; signed char* bf3; signed char* bf4;
};

__device__ __forceinline__ void prep_all_body(const PrepArgs& a, int i) {
  if (i < 704) {
    const int off[6] = {0, 64, 192, 320, 512, 704};
    int l = 0;
    while (i >= off[l + 1]) ++l;
    int c = i - off[l];
    float iv = __fdiv_rn(a.bng[l][c], __fsqrt_rn(__fadd_rn(a.bnv[l][c], 1e-5f)));
    float cb = __fsub_rn(a.bnb[l][c], __fmul_rn(a.bnm[l][c], iv));
    if (l == 0) { a.inv1[c] = iv; a.cc1[c] = cb; }
    else if (l == 4) { a.inv5[c] = iv; a.cc5[c] = cb; }
    else {
      auto pred = [&](int v_) {
        return __fadd_rn(__fmul_rn((float)v_, iv), cb) > 0.f;
      };
      int Tx, fl;
      if (iv == 0.f) { Tx = pred(0) ? -100000 : 100000; fl = 0; }
      else if (iv > 0.f) {
        if (pred(-2048)) { Tx = -100000; fl = 0; }
        else if (!pred(2048)) { Tx = 100000; fl = 0; }
        else {
          int lo = -2048, hi = 2048;
          while (hi - lo > 1) { int md = (lo + hi) >> 1; if (pred(md)) hi = md; else lo = md; }
          Tx = hi; fl = 0;   // bit = val >= Tx
        }
      } else {
        if (pred(2048)) { Tx = -100000; fl = -1; }
        else if (!pred(-2048)) { Tx = 100000; fl = -1; }
        else {
          int lo = -2048, hi = 2048;
          while (hi - lo > 1) { int md = (lo + hi) >> 1; if (pred(md)) lo = md; else hi = md; }
          Tx = lo ^ -1; fl = -1;   // bit = val <= lo  <=>  (val^-1) >= (~lo)
        }
      }
      a.thr[l - 1][c] = Tx; a.flp[l - 1][c] = fl;
    }
    return;
  }
  int j = i - 704;
  if (j >= 7488) return;
  const int poff[5] = {0, 1152, 3456, 6912, 7488};
  const int ICt[4] = {64, 128, 128, 192};
  const int Kt[4]  = {9, 9, 9, 1};
  const int Wt[4]  = {1, 2, 2, 3};
  int l = 0;
  while (j >= poff[l + 1]) ++l;
  int idx = j - poff[l];
  int W = Wt[l], K = Kt[l], IC = ICt[l];
  int wi = idx % W;
  int rest = idx / W;
  int t = rest % K;
  int oc = rest / K;
  u64 p = 0, z = 0;
  int icbase = wi * 64;
  int nb = IC - icbase; if (nb > 64) nb = 64;
  const float* w = a.w[l];
  for (int b = 0; b < nb; ++b) {
    float f = w[((size_t)oc * IC + (icbase + b)) * K + t];
    if (f > 0.f) p |= (1ull << b);
    else if (f == 0.f) z |= (1ull << b);
  }
  a.wp[l][idx] = p;
  a.wz[l][idx] = z;
  if (z) atomicOr(a.flags + l, 1u);
}

// 16x16x64 B-fragments (conv3/conv4 — verified mapping).
template <int CINW, int COUT>
__device__ __forceinline__ void prep_bfrag_body(const float* __restrict__ w,
                                                signed char* __restrict__ bf, int idx) {
  constexpr int NKC = 9 * CINW;
  constexpr int NT = COUT / 16;
  constexpr int CIN = 64 * CINW;
  if (idx >= NT * NKC * 64) return;
  int lane = idx & 63;
  int rest = idx >> 6;
  int kc = rest % NKC;
  int t = rest / NKC;
  int tap = kc / CINW, wd = kc % CINW;
  int n = t * 16 + (lane & 15);
  int icb = wd * 64 + (lane >> 4) * 16;
  signed char* dst = bf + (size_t)idx * 16;
#pragma unroll
  for (int i = 0; i < 16; ++i) {
    float f = w[((size_t)n * CIN + icb + i) * 9 + tap];
    dst[i] = (f > 0.f) ? 1 : ((f < 0.f) ? -1 : 0);
  }
}

// 32x32x32 B-fragments (conv2 — verified).
__device__ __forceinline__ void prep_bfrag32_body(const float* __restrict__ w,
                                                  signed char* __restrict__ bf, int idx) {
  if (idx >= 4 * 18 * 64) return;
  int lane = idx & 63;
  int rest = idx >> 6;
  int s = rest % 18;
  int t = rest / 18;
  int oc = t * 32 + (lane & 31);
  int kbase = s * 32 + (lane >> 5) * 16;
  signed char* dst = bf + (size_t)idx * 16;
#pragma unroll
  for (int i = 0; i < 16; ++i) {
    int k = kbase + i;
    int ch = k & 63, tap = k >> 6;
    float f = w[((size_t)oc * 64 + ch) * 9 + tap];
    dst[i] = (f > 0.f) ? 1 : ((f < 0.f) ? -1 : 0);
  }
}

// ---------------------------------------------------------------------------
// Fused front kernel: pad_x (blocks 0..8191) + all preps (by block range).
// ---------------------------------------------------------------------------
__global__ __launch_bounds__(256) void front(PrepArgs a) {
  int b = blockIdx.x, tid = threadIdx.x;
  if (b < 8192) {                       // pad_x: 128*128*128 elements
    int idx = b * 256 + tid;
    int c = idx & 127, r = (idx >> 7) & 127, n = idx >> 14;
    a.xpad[((size_t)n * 130 + r + 1) * 136 + c + 1] = a.x[idx];
    return;
  }
  b -= 8192;
  if (b < 32) { prep_all_body(a, b * 256 + tid); return; }
  b -= 32;
  if (b < 18) { prep_bfrag32_body(a.w[0], a.bf2x, b * 256 + tid); return; }
  b -= 18;
  if (b < 36) { prep_bfrag_body<2, 128>(a.w[1], a.bf3, b * 256 + tid); return; }
  b -= 36;
  if (b < 54) { prep_bfrag_body<2, 192>(a.w[2], a.bf4, b * 256 + tid); return; }
}

// ---------------------------------------------------------------------------
// conv1 (verified): fp32 1->64ch 3x3 s2 + bias + BN threshold -> padded pack.
// ---------------------------------------------------------------------------
__global__ __launch_bounds__(256) void conv1_bin(
    const float* __restrict__ xpad, const float* __restrict__ w1, const float* __restrict__ b1,
    const float* __restrict__ inv1, const float* __restrict__ cc1,
    u64* __restrict__ a1p) {
  int tid = threadIdx.x, lane = tid & 63;
  int rb = __builtin_amdgcn_readfirstlane(tid >> 6);
  int blk = blockIdx.x;                // 128*16
  int y = (blk % 16) * 4 + rb;
  int n = blk / 16;
  float W[9];
#pragma unroll
  for (int t = 0; t < 9; ++t) W[t] = w1[lane * 9 + t];
  float bias = b1[lane], iv = inv1[lane], cb = cc1[lane];
  const float* sb = xpad + ((size_t)n * 130 + 2 * y) * 136;
  float A[12], B[12], C[12];
  u64 rowm = 0;
  int xb = 0;

#define FLD(BUF, POFF)                                     \
  _Pragma("unroll") for (int _r = 0; _r < 3; ++_r)         \
  _Pragma("unroll") for (int _j = 0; _j < 4; ++_j)         \
    BUF[_r * 4 + _j] = sb[_r * 136 + (POFF) + _j];
#define FPX(XO, B0F, C0, B1F, C1, B2F, C2) {                          \
  float acc = 0.f;                                                    \
  _Pragma("unroll") for (int _r = 0; _r < 3; ++_r)                    \
    acc += B0F[_r * 4 + (C0)] * W[_r * 3 + 0]                         \
         + B1F[_r * 4 + (C1)] * W[_r * 3 + 1]                         \
         + B2F[_r * 4 + (C2)] * W[_r * 3 + 2];                        \
  float h = __fadd_rn(acc, bias);                                     \
  float bnv = __fadd_rn(__fmul_rn(h, iv), cb);                        \
  u64 _m = __ballot(bnv > 0.f);                                       \
  rowm = (lane == (XO)) ? _m : rowm; }
#define FSTEP(BA, BB, BC, POFF, XB)  \
  FLD(BC, (POFF) + 8);               \
  FPX((XB), BA, 0, BA, 1, BA, 2);    \
  FPX((XB) + 1, BA, 2, BA, 3, BB, 0);

  FLD(A, 0); FLD(B, 4);
  for (int g = 0; g < 10; ++g) {
    FSTEP(A, B, C, 0, xb);
    FSTEP(B, C, A, 4, xb + 2);
    FSTEP(C, A, B, 8, xb + 4);
    sb += 12; xb += 6;
  }
  FSTEP(A, B, C, 0, xb);
  FSTEP(B, C, A, 4, xb + 2);
  a1p[((size_t)n * 66 + (y + 1)) * 68 + lane + 1] = rowm;
#undef FLD
#undef FPX
#undef FSTEP
}

// ---------------------------------------------------------------------------
// conv2 via i8 MFMA 32x32x32, B staged in TWO 36 KB halves. Output words
// accumulated in registers; ONE 16 B int4 store per pixel at the end
// (contiguous full-line writes -> no HBM write amplification).
// C layout (verified): col=lane&31=oc, row=(reg&3)+8*(reg>>2)+4*(lane>>5)=px.
// ---------------------------------------------------------------------------
__global__ __launch_bounds__(256, 4) void bconv2_32(
    const u64* __restrict__ ain, const signed char* __restrict__ bf,
    const int* __restrict__ thr, const int* __restrict__ flp,
    u64* __restrict__ aout) {
  __shared__ int4v bs[2 * 18 * 64];     // 36864 B
  int tid = threadIdx.x, lane = tid & 63;
  int wv = __builtin_amdgcn_readfirstlane(tid >> 6);
  int pos = blockIdx.x * 4 + wv;        // 16384 = 128n * 64y * 2xg
  int xg = pos & 1;
  int y = (pos >> 1) & 63;
  int n = pos >> 7;
  int ln31 = lane & 31;
  int kg16 = (lane >> 5) * 16;
  int px = xg * 32 + ln31;

  const int4v* bfv = (const int4v*)bf;
  // preload stage 0 (t=0,1): 9 int4v per thread
  int4v breg[9];
#pragma unroll
  for (int i = 0; i < 9; ++i) breg[i] = bfv[tid + i * 256];

  // A fragments: af[s], s = tap*2 + h; k = tap*64 + h*32 + kg16 + i
  const u64* abase = ain + ((size_t)n * 66 + y) * 68 + px;
  int4v af[18];
#pragma unroll
  for (int tap = 0; tap < 9; ++tap) {
    int dy = tap / 3, dx = tap % 3;
    u64 aw = abase[(size_t)dy * 68 + dx];
#pragma unroll
    for (int h = 0; h < 2; ++h) {
      u32 t16 = (u32)(aw >> (h * 32 + kg16)) & 0xFFFFu;
      int4v v;
      v.x = (int)((((t16      ) & 0xFu) * 0x00204081u) & 0x01010101u);
      v.y = (int)((((t16 >> 4 ) & 0xFu) * 0x00204081u) & 0x01010101u);
      v.z = (int)((((t16 >> 8 ) & 0xFu) * 0x00204081u) & 0x01010101u);
      v.w = (int)((((t16 >> 12) & 0xFu) * 0x00204081u) & 0x01010101u);
      af[tap * 2 + h] = v;
    }
  }

  int txv[4], flv[4];
#pragma unroll
  for (int t = 0; t < 4; ++t) { txv[t] = thr[t * 32 + ln31]; flv[t] = flp[t * 32 + ln31]; }

  u32 ow4[4];

#define C2_EPI(T, CREG) {                                             \
  int tx = txv[T], fl = flv[T];                                       \
  u32 oww = 0;                                                        \
  _Pragma("unroll") for (int r = 0; r < 16; ++r) {                    \
    int plo = (r & 3) + 8 * (r >> 2);                                 \
    u64 bal = __ballot((CREG[r] ^ fl) >= tx);                         \
    u32 wlo = (u32)bal, whi = (u32)(bal >> 32);                       \
    oww = (lane == plo) ? wlo : oww;                                  \
    oww = (lane == plo + 4) ? whi : oww;                              \
  }                                                                   \
  ow4[T] = oww; }

  // ---- stage 0: t = 0,1 ----
#pragma unroll
  for (int i = 0; i < 9; ++i) bs[tid + i * 256] = breg[i];
  __syncthreads();
  // issue stage-1 loads (t=2,3) under stage-0 compute
#pragma unroll
  for (int i = 0; i < 9; ++i) breg[i] = bfv[2 * 18 * 64 + tid + i * 256];

#pragma unroll
  for (int t = 0; t < 2; ++t) {
    int16v c = {0, 0, 0, 0, 0, 0, 0, 0, 0, 0, 0, 0, 0, 0, 0, 0};
#pragma unroll
    for (int s = 0; s < 18; ++s) {
      int4v bb = bs[(t * 18 + s) * 64 + lane];
      c = __builtin_amdgcn_mfma_i32_32x32x32_i8(af[s], bb, c, 0, 0, 0);
    }
    C2_EPI(t, c)
  }

  // ---- stage 1: t = 2,3 ----
  __syncthreads();
#pragma unroll
  for (int i = 0; i < 9; ++i) bs[tid + i * 256] = breg[i];
  __syncthreads();
#pragma unroll
  for (int t = 2; t < 4; ++t) {
    int16v c = {0, 0, 0, 0, 0, 0, 0, 0, 0, 0, 0, 0, 0, 0, 0, 0};
#pragma unroll
    for (int s = 0; s < 18; ++s) {
      int4v bb = bs[((t - 2) * 18 + s) * 64 + lane];
      c = __builtin_amdgcn_mfma_i32_32x32x32_i8(af[s], bb, c, 0, 0, 0);
    }
    C2_EPI(t, c)
  }
#undef C2_EPI

  if (lane < 32) {
    int xx = xg * 32 + lane;
    u32* out32 = (u32*)aout;
    int4v ov;
    ov.x = (int)ow4[0]; ov.y = (int)ow4[1]; ov.z = (int)ow4[2]; ov.w = (int)ow4[3];
    *(int4v*)(out32 + (((size_t)n * 66 + (y + 1)) * 68 + (xx + 1)) * 4) = ov;
  }
}

// ---------------------------------------------------------------------------
// conv3/conv4 via 16x16x64 i8 MFMA (verified, unchanged).
// ---------------------------------------------------------------------------
template <int CINW, int COUT, int STRIDE, int IN_HW, int OUT_HW, int MT, int TSTG, int OPAD>
__global__ __launch_bounds__(256) void bconv_mfma(
    const u64* __restrict__ ain, const signed char* __restrict__ bf,
    const int* __restrict__ thr, const int* __restrict__ flp,
    u64* __restrict__ aout) {
  constexpr int IPW = IN_HW + 4;
  constexpr int NKC = 9 * CINW;
  constexpr int NT = COUT / 16;
  constexpr int NSTG = NT / TSTG;
  constexpr int OCW = (COUT + 63) / 64;
  constexpr int XG = OUT_HW / (16 * MT);
  constexpr int FRAG = TSTG * NKC * 64;
  constexpr int CPT = (FRAG + 255) / 256;
  constexpr int NW32 = NT / 2;
  __shared__ int4v bs[FRAG];

  int tid = threadIdx.x, lane = tid & 63;
  int wv = __builtin_amdgcn_readfirstlane(tid >> 6);
  int pos = blockIdx.x * 4 + wv;
  int xg = pos % XG;
  int rest = pos / XG;
  int y = rest % OUT_HW;
  int n = rest / OUT_HW;
  int m = lane & 15;
  int kg = lane >> 4;

  const int4v* bfv = (const int4v*)bf;

  int4v breg[CPT];
#pragma unroll
  for (int i = 0; i < CPT; ++i) {
    int ix = tid + i * 256;
    if (FRAG % 256 == 0 || ix < FRAG) breg[i] = bfv[ix];
  }

  int4v af[MT * NKC];
#pragma unroll
  for (int mt = 0; mt < MT; ++mt) {
    int x = (xg * MT + mt) * 16 + m;
    const u64* abase = ain + (((size_t)n * (IN_HW + 2) + STRIDE * y) * IPW
                              + (size_t)STRIDE * x) * CINW;
#pragma unroll
    for (int dy = 0; dy < 3; ++dy)
#pragma unroll
      for (int dx = 0; dx < 3; ++dx)
#pragma unroll
        for (int wd = 0; wd < CINW; ++wd) {
          u64 aw = abase[((size_t)dy * IPW + dx) * CINW + wd];
          u32 t16 = (u32)(aw >> (kg * 16)) & 0xFFFFu;
          int4v v;
          v.x = (int)((((t16      ) & 0xFu) * 0x00204081u) & 0x01010101u);
          v.y = (int)((((t16 >> 4 ) & 0xFu) * 0x00204081u) & 0x01010101u);
          v.z = (int)((((t16 >> 8 ) & 0xFu) * 0x00204081u) & 0x01010101u);
          v.w = (int)((((t16 >> 12) & 0xFu) * 0x00204081u) & 0x01010101u);
          af[mt * NKC + (dy * 3 + dx) * CINW + wd] = v;
        }
  }

  u32 acc32[MT][NW32];
#pragma unroll
  for (int mt = 0; mt < MT; ++mt)
#pragma unroll
    for (int wl = 0; wl < NW32; ++wl) acc32[mt][wl] = 0;

#pragma unroll
  for (int s = 0; s < NSTG; ++s) {
    __syncthreads();
#pragma unroll
    for (int i = 0; i < CPT; ++i) {
      int ix = tid + i * 256;
      if (FRAG % 256 == 0 || ix < FRAG) bs[ix] = breg[i];
    }
    __syncthreads();
    if (s + 1 < NSTG) {
      const int4v* src = bfv + (size_t)(s + 1) * FRAG;
#pragma unroll
      for (int i = 0; i < CPT; ++i) {
        int ix = tid + i * 256;
        if (FRAG % 256 == 0 || ix < FRAG) breg[i] = src[ix];
      }
    }
#pragma unroll
    for (int tl = 0; tl < TSTG; ++tl) {
      int4v c[MT];
#pragma unroll
      for (int mt = 0; mt < MT; ++mt) c[mt] = (int4v){0, 0, 0, 0};
#pragma unroll
      for (int kc = 0; kc < NKC; ++kc) {
        int4v bb = bs[(tl * NKC + kc) * 64 + lane];
#pragma unroll
        for (int mt = 0; mt < MT; ++mt)
          c[mt] = __builtin_amdgcn_mfma_i32_16x16x64_i8(af[mt * NKC + kc], bb, c[mt], 0, 0, 0);
      }
      const int t = s * TSTG + tl;
      int tx = thr[t * 16 + m];
      int fl = flp[t * 16 + m];
#pragma unroll
      for (int mt = 0; mt < MT; ++mt) {
        u64 b0 = __ballot((c[mt].x ^ fl) >= tx);
        u64 b1 = __ballot((c[mt].y ^ fl) >= tx);
        u64 b2 = __ballot((c[mt].z ^ fl) >= tx);
        u64 b3 = __ballot((c[mt].w ^ fl) >= tx);
        u64 s01 = (m & 1) ? b1 : b0;
        u64 s23 = (m & 1) ? b3 : b2;
        u64 bsel = (m & 2) ? s23 : s01;
        u32 slice = (u32)(bsel >> ((m >> 2) * 16)) & 0xFFFFu;
        acc32[mt][t >> 1] |= slice << ((t & 1) * 16);
      }
    }
  }

  if (kg == 0) {
    u32* out32 = (u32*)aout;
#pragma unroll
    for (int mt = 0; mt < MT; ++mt) {
      int x = (xg * MT + mt) * 16 + m;
      size_t px32;
      if (OPAD)
        px32 = (((size_t)n * (OUT_HW + 2) + (y + 1)) * (OUT_HW + 4) + (x + 1)) * (OCW * 2);
      else
        px32 = (((size_t)n * OUT_HW + y) * OUT_HW + x) * (OCW * 2);
#pragma unroll
      for (int wl = 0; wl < NW32; ++wl)
        out32[px32 + wl] = acc32[mt][wl];
    }
  }
}

// ---------------------------------------------------------------------------
// conv5 (verified): binarized 1x1 + BN + ReLU + partial pool.
// ---------------------------------------------------------------------------
#define NCH5 8
__global__ __launch_bounds__(192) void bconv5_pool(
    const u64* __restrict__ ain, const u64* __restrict__ wp, const u64* __restrict__ wz,
    const u32* __restrict__ flag, const float* __restrict__ inv5, const float* __restrict__ cc5,
    float* __restrict__ partial) {
  int n = blockIdx.x / NCH5, ch = blockIdx.x % NCH5;
  int oc = threadIdx.x;
  u64 W0 = wp[oc * 3], W1 = wp[oc * 3 + 1], W2 = wp[oc * 3 + 2];
  bool anyz = (*flag != 0u);
  float iv = inv5[oc], cb = cc5[oc];
  const u64* sb = ain + ((size_t)n * 1024 + ch * 128) * 3;
  u64 A0, A1, A2, B0, B1, B2, C0, C1, C2;
  float acc = 0.f;
#define LD5(P, a0_, a1_, a2_) { a0_ = sb[(P) * 3]; a1_ = sb[(P) * 3 + 1]; a2_ = sb[(P) * 3 + 2]; }
#define PX5(a0_, a1_, a2_) {                                                   \
  int _pa = __popcll(a0_) + __popcll(a1_) + __popcll(a2_);                     \
  int _s = __popcll(a0_ & W0) + __popcll(a1_ & W1) + __popcll(a2_ & W2);       \
  int _val = 2 * _s - _pa;                                                     \
  if (anyz) _val += __popcll(a0_ & wz[oc * 3]) + __popcll(a1_ & wz[oc * 3 + 1])\
                  + __popcll(a2_ & wz[oc * 3 + 2]);                            \
  float _b = __fadd_rn(__fmul_rn((float)_val, iv), cb);                        \
  acc += fmaxf(_b, 0.f); }
  LD5(0, A0, A1, A2); LD5(1, B0, B1, B2);
  for (int g = 0; g < 42; ++g) {
    LD5(2, C0, C1, C2); PX5(A0, A1, A2);
    LD5(3, A0, A1, A2); PX5(B0, B1, B2);
    LD5(4, B0, B1, B2); PX5(C0, C1, C2);
    sb += 9;
  }
  PX5(A0, A1, A2); PX5(B0, B1, B2);
  partial[((size_t)n * NCH5 + ch) * 192 + oc] = acc;
#undef LD5
#undef PX5
}

// ---------------------------------------------------------------------------
// Fused reduce + head (verified).
// ---------------------------------------------------------------------------
__global__ __launch_bounds__(192) void head2(
    const float* __restrict__ partial,
    const float* __restrict__ w6, const float* __restrict__ b6,
    const float* __restrict__ fw, const float* __restrict__ fb,
    float* __restrict__ out) {
  __shared__ float pool_s[192];
  __shared__ float h6s[12];
  __shared__ float lgs[12];
  int n = blockIdx.x, t = threadIdx.x;
  float s = 0.f;
#pragma unroll
  for (int ch = 0; ch < NCH5; ++ch) s += partial[((size_t)n * NCH5 + ch) * 192 + t];
  pool_s[t] = s;
  __syncthreads();
  if (t < 12) {
    float a = 0.f;
    for (int c = 0; c < 192; ++c) a += pool_s[c] * w6[t * 192 + c];
    h6s[t] = b6[t] + a * (1.0f / 1024.0f);
  }
  __syncthreads();
  if (t < 12) {
    float s2 = fb[t];
    for (int k = 0; k < 12; ++k) s2 += h6s[k] * fw[t * 12 + k];
    lgs[t] = s2;
  }
  __syncthreads();
  if (t == 0) {
    float mx = -1e30f;
    for (int j = 0; j < 12; ++j) mx = fmaxf(mx, lgs[j]);
    float e[12], se = 0.f;
    for (int j = 0; j < 12; ++j) { e[j] = expf(lgs[j] - mx); se += e[j]; }
    for (int j = 0; j < 12; ++j) out[n * 12 + j] = e[j] / se;
  }
}

// ---------------------------------------------------------------------------
// Launch
// ---------------------------------------------------------------------------
extern "C" void kernel_launch(void* const* d_in, const int* in_sizes, int n_in,
                              void* d_out, int out_size, void* d_ws, size_t ws_size,
                              hipStream_t stream) {
  const float* x   = (const float*)d_in[0];
  const float* w1  = (const float*)d_in[1];
  const float* b1  = (const float*)d_in[2];
  const float* w2  = (const float*)d_in[3];
  const float* w3  = (const float*)d_in[4];
  const float* w4  = (const float*)d_in[5];
  const float* w5  = (const float*)d_in[6];
  const float* w6  = (const float*)d_in[7];
  const float* b6  = (const float*)d_in[8];
  const float* fcw = (const float*)d_in[9];
  const float* fcb = (const float*)d_in[10];
  float* out = (float*)d_out;

  char* ws = (char*)d_ws;
  size_t off = 0;
  auto alloc = [&](size_t bytes) -> void* {
    void* p = ws + off;
    off += (bytes + 255) & ~(size_t)255;
    return p;
  };
  size_t xp_sz = (size_t)128 * 130 * 136 * 4;
  size_t a1_sz = (size_t)128 * 66 * 68 * 1 * 8;
  size_t a2_sz = (size_t)128 * 66 * 68 * 2 * 8;
  size_t a3_sz = (size_t)128 * 34 * 36 * 2 * 8;
  float* xpad = (float*)alloc(xp_sz);
  u64* a1p = (u64*)alloc(a1_sz);
  u64* a2p = (u64*)alloc(a2_sz);
  u64* a3p = (u64*)alloc(a3_sz);
  size_t zero_sz = xp_sz + a1_sz + a2_sz + a3_sz;
  u64* a4p = (u64*)alloc((size_t)128 * 32 * 32 * 3 * 8);
  float* partial = (float*)alloc((size_t)128 * NCH5 * 192 * 4);
  float* inv1 = (float*)alloc(64 * 4);
  float* cc1  = (float*)alloc(64 * 4);
  float* inv5 = (float*)alloc(192 * 4);
  float* cc5  = (float*)alloc(192 * 4);
  int* thr2 = (int*)alloc(128 * 4); int* flp2 = (int*)alloc(128 * 4);
  int* thr3 = (int*)alloc(128 * 4); int* flp3 = (int*)alloc(128 * 4);
  int* thr4 = (int*)alloc(192 * 4); int* flp4 = (int*)alloc(192 * 4);
  u64* wp2 = (u64*)alloc(128 * 9 * 1 * 8);
  u64* wz2 = (u64*)alloc(128 * 9 * 1 * 8);
  u64* wp3 = (u64*)alloc(128 * 9 * 2 * 8);
  u64* wz3 = (u64*)alloc(128 * 9 * 2 * 8);
  u64* wp4 = (u64*)alloc(192 * 9 * 2 * 8);
  u64* wz4 = (u64*)alloc(192 * 9 * 2 * 8);
  u64* wp5 = (u64*)alloc(192 * 1 * 3 * 8);
  u64* wz5 = (u64*)alloc(192 * 1 * 3 * 8);
  u32* flags = (u32*)alloc(4 * sizeof(u32));
  signed char* bf2x = (signed char*)alloc((size_t)4 * 18 * 64 * 16);
  signed char* bf3 = (signed char*)alloc((size_t)8 * 18 * 64 * 16);
  signed char* bf4 = (signed char*)alloc((size_t)12 * 18 * 64 * 16);
  (void)ws_size; (void)n_in; (void)in_sizes; (void)out_size;

  hipMemsetAsync(xpad, 0, zero_sz, stream);
  hipMemsetAsync(flags, 0, 4 * sizeof(u32), stream);

  PrepArgs pa;
  for (int l = 0; l < 5; ++l) {
    pa.bng[l] = (const float*)d_in[11 + 4 * l + 0];
    pa.bnb[l] = (const float*)d_in[11 + 4 * l + 1];
    pa.bnm[l] = (const float*)d_in[11 + 4 * l + 2];
    pa.bnv[l] = (const float*)d_in[11 + 4 * l + 3];
  }
  pa.inv1 = inv1; pa.cc1 = cc1; pa.inv5 = inv5; pa.cc5 = cc5;
  pa.thr[0] = thr2; pa.flp[0] = flp2;
  pa.thr[1] = thr3; pa.flp[1] = flp3;
  pa.thr[2] = thr4; pa.flp[2] = flp4;
  pa.w[0] = w2; pa.w[1] = w3; pa.w[2] = w4; pa.w[3] = w5;
  pa.wp[0] = wp2; pa.wp[1] = wp3; pa.wp[2] = wp4; pa.wp[3] = wp5;
  pa.wz[0] = wz2; pa.wz[1] = wz3; pa.wz[2] = wz4; pa.wz[3] = wz5;
  pa.flags = flags;
  pa.x = x; pa.xpad = xpad;
  pa.bf2x = bf2x; pa.bf3 = bf3; pa.bf4 = bf4;

  // fused front-end: pad_x + prep_all + all B-fragment preps
  front<<<8192 + 32 + 18 + 36 + 54, 256, 0, stream>>>(pa);

  conv1_bin<<<128 * 16, 256, 0, stream>>>(xpad, w1, b1, inv1, cc1, a1p);

  // conv2: 32x32x32 MFMA, 2-stage 36 KB LDS, single 16B store per pixel.
  bconv2_32<<<4096, 256, 0, stream>>>(a1p, bf2x, thr2, flp2, a2p);

  // conv3: 128->128ch, 64->32, s2. MT=1, TSTG=1 (8 stages). 2048 blocks.
  bconv_mfma<2, 128, 2, 64, 32, 1, 1, 1><<<2048, 256, 0, stream>>>(
      a2p, bf3, thr3, flp3, a3p);

  // conv4: 128->192ch, 32x32, s1. MT=1, TSTG=1 (12 stages). 2048 blocks.
  bconv_mfma<2, 192, 1, 32, 32, 1, 1, 0><<<2048, 256, 0, stream>>>(
      a3p, bf4, thr4, flp4, a4p);

  bconv5_pool<<<128 * NCH5, 192, 0, stream>>>(a4p, wp5, wz5, flags + 3, inv5, cc5, partial);

  head2<<<128, 192, 0, stream>>>(partial, w6, b6, fcw, fcb, out);
}

// Round 20
// 183.598 us; speedup vs baseline: 1.1280x; 1.1280x over previous
//
#include <hip/hip_runtime.h>
#include <cstdint>

using u64 = unsigned long long;
using u32 = unsigned int;
typedef __attribute__((ext_vector_type(4))) int int4v;
typedef __attribute__((ext_vector_type(16))) int int16v;

// ---------------------------------------------------------------------------
// Prep bodies (called from the fused front kernel).
// ---------------------------------------------------------------------------
struct PrepArgs {
  const float* bng[5]; const float* bnb[5]; const float* bnm[5]; const float* bnv[5];
  float* inv1; float* cc1; float* inv5; float* cc5;
  int* thr[3]; int* flp[3];
  const float* w[4];
  u64* wp[4]; u64* wz[4];
  u32* flags;
  const float* x; float* xpad;
  signed char* bf2x; signed char* bf3; signed char* bf4;
};

__device__ __forceinline__ void prep_all_body(const PrepArgs& a, int i) {
  if (i < 704) {
    const int off[6] = {0, 64, 192, 320, 512, 704};
    int l = 0;
    while (i >= off[l + 1]) ++l;
    int c = i - off[l];
    float iv = __fdiv_rn(a.bng[l][c], __fsqrt_rn(__fadd_rn(a.bnv[l][c], 1e-5f)));
    float cb = __fsub_rn(a.bnb[l][c], __fmul_rn(a.bnm[l][c], iv));
    if (l == 0) { a.inv1[c] = iv; a.cc1[c] = cb; }
    else if (l == 4) { a.inv5[c] = iv; a.cc5[c] = cb; }
    else {
      auto pred = [&](int v_) {
        return __fadd_rn(__fmul_rn((float)v_, iv), cb) > 0.f;
      };
      int Tx, fl;
      if (iv == 0.f) { Tx = pred(0) ? -100000 : 100000; fl = 0; }
      else if (iv > 0.f) {
        if (pred(-2048)) { Tx = -100000; fl = 0; }
        else if (!pred(2048)) { Tx = 100000; fl = 0; }
        else {
          int lo = -2048, hi = 2048;
          while (hi - lo > 1) { int md = (lo + hi) >> 1; if (pred(md)) hi = md; else lo = md; }
          Tx = hi; fl = 0;   // bit = val >= Tx
        }
      } else {
        if (pred(2048)) { Tx = -100000; fl = -1; }
        else if (!pred(-2048)) { Tx = 100000; fl = -1; }
        else {
          int lo = -2048, hi = 2048;
          while (hi - lo > 1) { int md = (lo + hi) >> 1; if (pred(md)) lo = md; else hi = md; }
          Tx = lo ^ -1; fl = -1;   // bit = val <= lo  <=>  (val^-1) >= (~lo)
        }
      }
      a.thr[l - 1][c] = Tx; a.flp[l - 1][c] = fl;
    }
    return;
  }
  int j = i - 704;
  if (j >= 7488) return;
  const int poff[5] = {0, 1152, 3456, 6912, 7488};
  const int ICt[4] = {64, 128, 128, 192};
  const int Kt[4]  = {9, 9, 9, 1};
  const int Wt[4]  = {1, 2, 2, 3};
  int l = 0;
  while (j >= poff[l + 1]) ++l;
  int idx = j - poff[l];
  int W = Wt[l], K = Kt[l], IC = ICt[l];
  int wi = idx % W;
  int rest = idx / W;
  int t = rest % K;
  int oc = rest / K;
  u64 p = 0, z = 0;
  int icbase = wi * 64;
  int nb = IC - icbase; if (nb > 64) nb = 64;
  const float* w = a.w[l];
  for (int b = 0; b < nb; ++b) {
    float f = w[((size_t)oc * IC + (icbase + b)) * K + t];
    if (f > 0.f) p |= (1ull << b);
    else if (f == 0.f) z |= (1ull << b);
  }
  a.wp[l][idx] = p;
  a.wz[l][idx] = z;
  if (z) atomicOr(a.flags + l, 1u);
}

// 32x32x32 B-fragments for conv2 (CIN=64; verified).
__device__ __forceinline__ void prep_bfrag32_body(const float* __restrict__ w,
                                                  signed char* __restrict__ bf, int idx) {
  if (idx >= 4 * 18 * 64) return;
  int lane = idx & 63;
  int rest = idx >> 6;
  int s = rest % 18;
  int t = rest / 18;
  int oc = t * 32 + (lane & 31);
  int kbase = s * 32 + (lane >> 5) * 16;
  signed char* dst = bf + (size_t)idx * 16;
#pragma unroll
  for (int i = 0; i < 16; ++i) {
    int k = kbase + i;
    int ch = k & 63, tap = k >> 6;
    float f = w[((size_t)oc * 64 + ch) * 9 + tap];
    dst[i] = (f > 0.f) ? 1 : ((f < 0.f) ? -1 : 0);
  }
}

// 32x32x32 B-fragments for conv3/conv4 (CIN=128): k = tap*128 + ch; slice s
// covers k in [s*32, s*32+32), lane-half h gives +16. Same mapping as A-side.
template <int COUT>
__device__ __forceinline__ void prep_bfrag32b_body(const float* __restrict__ w,
                                                   signed char* __restrict__ bf, int idx) {
  constexpr int NT = COUT / 32;
  if (idx >= NT * 36 * 64) return;
  int lane = idx & 63;
  int rest = idx >> 6;
  int s = rest % 36;
  int t = rest / 36;
  int oc = t * 32 + (lane & 31);
  int kbase = s * 32 + (lane >> 5) * 16;
  signed char* dst = bf + (size_t)idx * 16;
#pragma unroll
  for (int i = 0; i < 16; ++i) {
    int k = kbase + i;
    int ch = k % 128, tap = k / 128;
    float f = w[((size_t)oc * 128 + ch) * 9 + tap];
    dst[i] = (f > 0.f) ? 1 : ((f < 0.f) ? -1 : 0);
  }
}

// ---------------------------------------------------------------------------
// Fused front kernel: pad_x (blocks 0..8191) + all preps (by block range).
// ---------------------------------------------------------------------------
__global__ __launch_bounds__(256) void front(PrepArgs a) {
  int b = blockIdx.x, tid = threadIdx.x;
  if (b < 8192) {                       // pad_x: 128*128*128 elements
    int idx = b * 256 + tid;
    int c = idx & 127, r = (idx >> 7) & 127, n = idx >> 14;
    a.xpad[((size_t)n * 130 + r + 1) * 136 + c + 1] = a.x[idx];
    return;
  }
  b -= 8192;
  if (b < 32) { prep_all_body(a, b * 256 + tid); return; }
  b -= 32;
  if (b < 18) { prep_bfrag32_body(a.w[0], a.bf2x, b * 256 + tid); return; }
  b -= 18;
  if (b < 36) { prep_bfrag32b_body<128>(a.w[1], a.bf3, b * 256 + tid); return; }
  b -= 36;
  if (b < 54) { prep_bfrag32b_body<192>(a.w[2], a.bf4, b * 256 + tid); return; }
}

// ---------------------------------------------------------------------------
// conv1 (verified): fp32 1->64ch 3x3 s2 + bias + BN threshold -> padded pack.
// ---------------------------------------------------------------------------
__global__ __launch_bounds__(256) void conv1_bin(
    const float* __restrict__ xpad, const float* __restrict__ w1, const float* __restrict__ b1,
    const float* __restrict__ inv1, const float* __restrict__ cc1,
    u64* __restrict__ a1p) {
  int tid = threadIdx.x, lane = tid & 63;
  int rb = __builtin_amdgcn_readfirstlane(tid >> 6);
  int blk = blockIdx.x;                // 128*16
  int y = (blk % 16) * 4 + rb;
  int n = blk / 16;
  float W[9];
#pragma unroll
  for (int t = 0; t < 9; ++t) W[t] = w1[lane * 9 + t];
  float bias = b1[lane], iv = inv1[lane], cb = cc1[lane];
  const float* sb = xpad + ((size_t)n * 130 + 2 * y) * 136;
  float A[12], B[12], C[12];
  u64 rowm = 0;
  int xb = 0;

#define FLD(BUF, POFF)                                     \
  _Pragma("unroll") for (int _r = 0; _r < 3; ++_r)         \
  _Pragma("unroll") for (int _j = 0; _j < 4; ++_j)         \
    BUF[_r * 4 + _j] = sb[_r * 136 + (POFF) + _j];
#define FPX(XO, B0F, C0, B1F, C1, B2F, C2) {                          \
  float acc = 0.f;                                                    \
  _Pragma("unroll") for (int _r = 0; _r < 3; ++_r)                    \
    acc += B0F[_r * 4 + (C0)] * W[_r * 3 + 0]                         \
         + B1F[_r * 4 + (C1)] * W[_r * 3 + 1]                         \
         + B2F[_r * 4 + (C2)] * W[_r * 3 + 2];                        \
  float h = __fadd_rn(acc, bias);                                     \
  float bnv = __fadd_rn(__fmul_rn(h, iv), cb);                        \
  u64 _m = __ballot(bnv > 0.f);                                       \
  rowm = (lane == (XO)) ? _m : rowm; }
#define FSTEP(BA, BB, BC, POFF, XB)  \
  FLD(BC, (POFF) + 8);               \
  FPX((XB), BA, 0, BA, 1, BA, 2);    \
  FPX((XB) + 1, BA, 2, BA, 3, BB, 0);

  FLD(A, 0); FLD(B, 4);
  for (int g = 0; g < 10; ++g) {
    FSTEP(A, B, C, 0, xb);
    FSTEP(B, C, A, 4, xb + 2);
    FSTEP(C, A, B, 8, xb + 4);
    sb += 12; xb += 6;
  }
  FSTEP(A, B, C, 0, xb);
  FSTEP(B, C, A, 4, xb + 2);
  a1p[((size_t)n * 66 + (y + 1)) * 68 + lane + 1] = rowm;
#undef FLD
#undef FPX
#undef FSTEP
}

// ---------------------------------------------------------------------------
// conv2 via i8 MFMA 32x32x32 (R18-exact, best measured): B in TWO 36 KB
// stages; per-t u32 stores inside the epilogue.
// C layout (verified): col=lane&31=oc, row=(reg&3)+8*(reg>>2)+4*(lane>>5)=px.
// ---------------------------------------------------------------------------
__global__ __launch_bounds__(256, 4) void bconv2_32(
    const u64* __restrict__ ain, const signed char* __restrict__ bf,
    const int* __restrict__ thr, const int* __restrict__ flp,
    u64* __restrict__ aout) {
  __shared__ int4v bs[2 * 18 * 64];     // 36864 B
  int tid = threadIdx.x, lane = tid & 63;
  int wv = __builtin_amdgcn_readfirstlane(tid >> 6);
  int pos = blockIdx.x * 4 + wv;        // 16384 = 128n * 64y * 2xg
  int xg = pos & 1;
  int y = (pos >> 1) & 63;
  int n = pos >> 7;
  int ln31 = lane & 31;
  int kg16 = (lane >> 5) * 16;
  int px = xg * 32 + ln31;

  const int4v* bfv = (const int4v*)bf;
  int4v breg[9];
#pragma unroll
  for (int i = 0; i < 9; ++i) breg[i] = bfv[tid + i * 256];

  const u64* abase = ain + ((size_t)n * 66 + y) * 68 + px;
  int4v af[18];
#pragma unroll
  for (int tap = 0; tap < 9; ++tap) {
    int dy = tap / 3, dx = tap % 3;
    u64 aw = abase[(size_t)dy * 68 + dx];
#pragma unroll
    for (int h = 0; h < 2; ++h) {
      u32 t16 = (u32)(aw >> (h * 32 + kg16)) & 0xFFFFu;
      int4v v;
      v.x = (int)((((t16      ) & 0xFu) * 0x00204081u) & 0x01010101u);
      v.y = (int)((((t16 >> 4 ) & 0xFu) * 0x00204081u) & 0x01010101u);
      v.z = (int)((((t16 >> 8 ) & 0xFu) * 0x00204081u) & 0x01010101u);
      v.w = (int)((((t16 >> 12) & 0xFu) * 0x00204081u) & 0x01010101u);
      af[tap * 2 + h] = v;
    }
  }

  int txv[4], flv[4];
#pragma unroll
  for (int t = 0; t < 4; ++t) { txv[t] = thr[t * 32 + ln31]; flv[t] = flp[t * 32 + ln31]; }

  u32* out32 = (u32*)aout;

#define C2_EPI(T, CREG) {                                             \
  int tx = txv[T], fl = flv[T];                                       \
  u32 oww = 0;                                                        \
  _Pragma("unroll") for (int r = 0; r < 16; ++r) {                    \
    int plo = (r & 3) + 8 * (r >> 2);                                 \
    u64 bal = __ballot((CREG[r] ^ fl) >= tx);                         \
    u32 wlo = (u32)bal, whi = (u32)(bal >> 32);                       \
    oww = (lane == plo) ? wlo : oww;                                  \
    oww = (lane == plo + 4) ? whi : oww;                              \
  }                                                                   \
  if (lane < 32) {                                                    \
    int xx = xg * 32 + lane;                                          \
    out32[(((size_t)n * 66 + (y + 1)) * 68 + (xx + 1)) * 4 + (T)] = oww; \
  } }

  // ---- stage 0: t = 0,1 ----
#pragma unroll
  for (int i = 0; i < 9; ++i) bs[tid + i * 256] = breg[i];
  __syncthreads();
#pragma unroll
  for (int i = 0; i < 9; ++i) breg[i] = bfv[2 * 18 * 64 + tid + i * 256];

#pragma unroll
  for (int t = 0; t < 2; ++t) {
    int16v c = {0, 0, 0, 0, 0, 0, 0, 0, 0, 0, 0, 0, 0, 0, 0, 0};
#pragma unroll
    for (int s = 0; s < 18; ++s) {
      int4v bb = bs[(t * 18 + s) * 64 + lane];
      c = __builtin_amdgcn_mfma_i32_32x32x32_i8(af[s], bb, c, 0, 0, 0);
    }
    C2_EPI(t, c)
  }

  // ---- stage 1: t = 2,3 ----
  __syncthreads();
#pragma unroll
  for (int i = 0; i < 9; ++i) bs[tid + i * 256] = breg[i];
  __syncthreads();
#pragma unroll
  for (int t = 2; t < 4; ++t) {
    int16v c = {0, 0, 0, 0, 0, 0, 0, 0, 0, 0, 0, 0, 0, 0, 0, 0};
#pragma unroll
    for (int s = 0; s < 18; ++s) {
      int4v bb = bs[((t - 2) * 18 + s) * 64 + lane];
      c = __builtin_amdgcn_mfma_i32_32x32x32_i8(af[s], bb, c, 0, 0, 0);
    }
    C2_EPI(t, c)
  }
#undef C2_EPI
}

// ---------------------------------------------------------------------------
// conv3/conv4 via i8 MFMA 32x32x32. Wave = one 32-px output row x all COUT oc.
// af[36] resident; B double-buffered in 2x36 KB LDS (one barrier per t-tile,
// next tile's copy issued before this tile's 36 MFMAs). Same verified
// fragment/epilogue math as conv2_32.
// ---------------------------------------------------------------------------
template <int COUT, int STRIDE, int IN_HW, int OPAD>
__global__ __launch_bounds__(256) void bconv34_32(
    const u64* __restrict__ ain, const signed char* __restrict__ bf,
    const int* __restrict__ thr, const int* __restrict__ flp,
    u64* __restrict__ aout) {
  constexpr int IPW = IN_HW + 4;
  constexpr int NT = COUT / 32;
  constexpr int TW = 36 * 64;           // int4v per t-tile
  constexpr int OW32 = COUT / 32;       // u32 words per px
  __shared__ int4v bs[2][TW];           // 73728 B
  int tid = threadIdx.x, lane = tid & 63;
  int wv = __builtin_amdgcn_readfirstlane(tid >> 6);
  int pos = blockIdx.x * 4 + wv;        // 128n * 32y
  int y = pos & 31;
  int n = pos >> 5;
  int ln31 = lane & 31;
  int h = lane >> 5;

  const int4v* bfv = (const int4v*)bf;

  // A fragments: slice s = tap*4+q; k = tap*128 + q*32 + h*16 + i
  const u64* abase = ain + (((size_t)n * (IN_HW + 2) + (size_t)STRIDE * y) * IPW
                            + (size_t)STRIDE * ln31) * 2;
  int4v af[36];
#pragma unroll
  for (int tap = 0; tap < 9; ++tap) {
    int dy = tap / 3, dx = tap % 3;
    u64 w0 = abase[((size_t)dy * IPW + dx) * 2 + 0];
    u64 w1 = abase[((size_t)dy * IPW + dx) * 2 + 1];
#pragma unroll
    for (int q = 0; q < 4; ++q) {
      int m2 = 2 * q + h;
      u64 aw = (m2 & 4) ? w1 : w0;
      int sh = (m2 & 3) * 16;
      u32 t16 = (u32)(aw >> sh) & 0xFFFFu;
      int4v v;
      v.x = (int)((((t16      ) & 0xFu) * 0x00204081u) & 0x01010101u);
      v.y = (int)((((t16 >> 4 ) & 0xFu) * 0x00204081u) & 0x01010101u);
      v.z = (int)((((t16 >> 8 ) & 0xFu) * 0x00204081u) & 0x01010101u);
      v.w = (int)((((t16 >> 12) & 0xFu) * 0x00204081u) & 0x01010101u);
      af[tap * 4 + q] = v;
    }
  }

  // stage t=0
#pragma unroll
  for (int i = 0; i < 9; ++i) bs[0][tid + i * 256] = bfv[tid + i * 256];
  __syncthreads();

  u32* out32 = (u32*)aout;
  size_t px32;
  if (OPAD)
    px32 = (((size_t)n * 34 + (y + 1)) * 36 + (ln31 + 1)) * OW32;
  else
    px32 = (((size_t)n * 32 + y) * 32 + ln31) * OW32;

#pragma unroll 1
  for (int t = 0; t < NT; ++t) {
    if (t + 1 < NT) {                   // copy next tile into other buffer
      const int4v* src = bfv + (size_t)(t + 1) * TW;
#pragma unroll
      for (int i = 0; i < 9; ++i) bs[(t + 1) & 1][tid + i * 256] = src[tid + i * 256];
    }
    int16v c = {0, 0, 0, 0, 0, 0, 0, 0, 0, 0, 0, 0, 0, 0, 0, 0};
#pragma unroll
    for (int s = 0; s < 36; ++s) {
      int4v bb = bs[t & 1][s * 64 + lane];
      c = __builtin_amdgcn_mfma_i32_32x32x32_i8(af[s], bb, c, 0, 0, 0);
    }
    int tx = thr[t * 32 + ln31];
    int fl = flp[t * 32 + ln31];
    u32 oww = 0;
#pragma unroll
    for (int r = 0; r < 16; ++r) {
      int plo = (r & 3) + 8 * (r >> 2);
      u64 bal = __ballot((c[r] ^ fl) >= tx);
      u32 wlo = (u32)bal, whi = (u32)(bal >> 32);
      oww = (lane == plo) ? wlo : oww;
      oww = (lane == plo + 4) ? whi : oww;
    }
    if (lane < 32) out32[px32 + t] = oww;
    __syncthreads();                    // all reads of bs[t&1] done
  }
}

// ---------------------------------------------------------------------------
// conv5 (verified): binarized 1x1 + BN + ReLU + partial pool.
// ---------------------------------------------------------------------------
#define NCH5 8
__global__ __launch_bounds__(192) void bconv5_pool(
    const u64* __restrict__ ain, const u64* __restrict__ wp, const u64* __restrict__ wz,
    const u32* __restrict__ flag, const float* __restrict__ inv5, const float* __restrict__ cc5,
    float* __restrict__ partial) {
  int n = blockIdx.x / NCH5, ch = blockIdx.x % NCH5;
  int oc = threadIdx.x;
  u64 W0 = wp[oc * 3], W1 = wp[oc * 3 + 1], W2 = wp[oc * 3 + 2];
  bool anyz = (*flag != 0u);
  float iv = inv5[oc], cb = cc5[oc];
  const u64* sb = ain + ((size_t)n * 1024 + ch * 128) * 3;
  u64 A0, A1, A2, B0, B1, B2, C0, C1, C2;
  float acc = 0.f;
#define LD5(P, a0_, a1_, a2_) { a0_ = sb[(P) * 3]; a1_ = sb[(P) * 3 + 1]; a2_ = sb[(P) * 3 + 2]; }
#define PX5(a0_, a1_, a2_) {                                                   \
  int _pa = __popcll(a0_) + __popcll(a1_) + __popcll(a2_);                     \
  int _s = __popcll(a0_ & W0) + __popcll(a1_ & W1) + __popcll(a2_ & W2);       \
  int _val = 2 * _s - _pa;                                                     \
  if (anyz) _val += __popcll(a0_ & wz[oc * 3]) + __popcll(a1_ & wz[oc * 3 + 1])\
                  + __popcll(a2_ & wz[oc * 3 + 2]);                            \
  float _b = __fadd_rn(__fmul_rn((float)_val, iv), cb);                        \
  acc += fmaxf(_b, 0.f); }
  LD5(0, A0, A1, A2); LD5(1, B0, B1, B2);
  for (int g = 0; g < 42; ++g) {
    LD5(2, C0, C1, C2); PX5(A0, A1, A2);
    LD5(3, A0, A1, A2); PX5(B0, B1, B2);
    LD5(4, B0, B1, B2); PX5(C0, C1, C2);
    sb += 9;
  }
  PX5(A0, A1, A2); PX5(B0, B1, B2);
  partial[((size_t)n * NCH5 + ch) * 192 + oc] = acc;
#undef LD5
#undef PX5
}

// ---------------------------------------------------------------------------
// Fused reduce + head (verified).
// ---------------------------------------------------------------------------
__global__ __launch_bounds__(192) void head2(
    const float* __restrict__ partial,
    const float* __restrict__ w6, const float* __restrict__ b6,
    const float* __restrict__ fw, const float* __restrict__ fb,
    float* __restrict__ out) {
  __shared__ float pool_s[192];
  __shared__ float h6s[12];
  __shared__ float lgs[12];
  int n = blockIdx.x, t = threadIdx.x;
  float s = 0.f;
#pragma unroll
  for (int ch = 0; ch < NCH5; ++ch) s += partial[((size_t)n * NCH5 + ch) * 192 + t];
  pool_s[t] = s;
  __syncthreads();
  if (t < 12) {
    float a = 0.f;
    for (int c = 0; c < 192; ++c) a += pool_s[c] * w6[t * 192 + c];
    h6s[t] = b6[t] + a * (1.0f / 1024.0f);
  }
  __syncthreads();
  if (t < 12) {
    float s2 = fb[t];
    for (int k = 0; k < 12; ++k) s2 += h6s[k] * fw[t * 12 + k];
    lgs[t] = s2;
  }
  __syncthreads();
  if (t == 0) {
    float mx = -1e30f;
    for (int j = 0; j < 12; ++j) mx = fmaxf(mx, lgs[j]);
    float e[12], se = 0.f;
    for (int j = 0; j < 12; ++j) { e[j] = expf(lgs[j] - mx); se += e[j]; }
    for (int j = 0; j < 12; ++j) out[n * 12 + j] = e[j] / se;
  }
}

// ---------------------------------------------------------------------------
// Launch
// ---------------------------------------------------------------------------
extern "C" void kernel_launch(void* const* d_in, const int* in_sizes, int n_in,
                              void* d_out, int out_size, void* d_ws, size_t ws_size,
                              hipStream_t stream) {
  const float* x   = (const float*)d_in[0];
  const float* w1  = (const float*)d_in[1];
  const float* b1  = (const float*)d_in[2];
  const float* w2  = (const float*)d_in[3];
  const float* w3  = (const float*)d_in[4];
  const float* w4  = (const float*)d_in[5];
  const float* w5  = (const float*)d_in[6];
  const float* w6  = (const float*)d_in[7];
  const float* b6  = (const float*)d_in[8];
  const float* fcw = (const float*)d_in[9];
  const float* fcb = (const float*)d_in[10];
  float* out = (float*)d_out;

  char* ws = (char*)d_ws;
  size_t off = 0;
  auto alloc = [&](size_t bytes) -> void* {
    void* p = ws + off;
    off += (bytes + 255) & ~(size_t)255;
    return p;
  };
  size_t xp_sz = (size_t)128 * 130 * 136 * 4;
  size_t a1_sz = (size_t)128 * 66 * 68 * 1 * 8;
  size_t a2_sz = (size_t)128 * 66 * 68 * 2 * 8;
  size_t a3_sz = (size_t)128 * 34 * 36 * 2 * 8;
  float* xpad = (float*)alloc(xp_sz);
  u64* a1p = (u64*)alloc(a1_sz);
  u64* a2p = (u64*)alloc(a2_sz);
  u64* a3p = (u64*)alloc(a3_sz);
  size_t zero_sz = xp_sz + a1_sz + a2_sz + a3_sz;
  u64* a4p = (u64*)alloc((size_t)128 * 32 * 32 * 3 * 8);
  float* partial = (float*)alloc((size_t)128 * NCH5 * 192 * 4);
  float* inv1 = (float*)alloc(64 * 4);
  float* cc1  = (float*)alloc(64 * 4);
  float* inv5 = (float*)alloc(192 * 4);
  float* cc5  = (float*)alloc(192 * 4);
  int* thr2 = (int*)alloc(128 * 4); int* flp2 = (int*)alloc(128 * 4);
  int* thr3 = (int*)alloc(128 * 4); int* flp3 = (int*)alloc(128 * 4);
  int* thr4 = (int*)alloc(192 * 4); int* flp4 = (int*)alloc(192 * 4);
  u64* wp2 = (u64*)alloc(128 * 9 * 1 * 8);
  u64* wz2 = (u64*)alloc(128 * 9 * 1 * 8);
  u64* wp3 = (u64*)alloc(128 * 9 * 2 * 8);
  u64* wz3 = (u64*)alloc(128 * 9 * 2 * 8);
  u64* wp4 = (u64*)alloc(192 * 9 * 2 * 8);
  u64* wz4 = (u64*)alloc(192 * 9 * 2 * 8);
  u64* wp5 = (u64*)alloc(192 * 1 * 3 * 8);
  u64* wz5 = (u64*)alloc(192 * 1 * 3 * 8);
  u32* flags = (u32*)alloc(4 * sizeof(u32));
  signed char* bf2x = (signed char*)alloc((size_t)4 * 18 * 64 * 16);
  signed char* bf3 = (signed char*)alloc((size_t)4 * 36 * 64 * 16);
  signed char* bf4 = (signed char*)alloc((size_t)6 * 36 * 64 * 16);
  (void)ws_size; (void)n_in; (void)in_sizes; (void)out_size;

  hipMemsetAsync(xpad, 0, zero_sz, stream);
  hipMemsetAsync(flags, 0, 4 * sizeof(u32), stream);

  PrepArgs pa;
  for (int l = 0; l < 5; ++l) {
    pa.bng[l] = (const float*)d_in[11 + 4 * l + 0];
    pa.bnb[l] = (const float*)d_in[11 + 4 * l + 1];
    pa.bnm[l] = (const float*)d_in[11 + 4 * l + 2];
    pa.bnv[l] = (const float*)d_in[11 + 4 * l + 3];
  }
  pa.inv1 = inv1; pa.cc1 = cc1; pa.inv5 = inv5; pa.cc5 = cc5;
  pa.thr[0] = thr2; pa.flp[0] = flp2;
  pa.thr[1] = thr3; pa.flp[1] = flp3;
  pa.thr[2] = thr4; pa.flp[2] = flp4;
  pa.w[0] = w2; pa.w[1] = w3; pa.w[2] = w4; pa.w[3] = w5;
  pa.wp[0] = wp2; pa.wp[1] = wp3; pa.wp[2] = wp4; pa.wp[3] = wp5;
  pa.wz[0] = wz2; pa.wz[1] = wz3; pa.wz[2] = wz4; pa.wz[3] = wz5;
  pa.flags = flags;
  pa.x = x; pa.xpad = xpad;
  pa.bf2x = bf2x; pa.bf3 = bf3; pa.bf4 = bf4;

  // fused front-end: pad_x + prep_all + all B-fragment preps
  front<<<8192 + 32 + 18 + 36 + 54, 256, 0, stream>>>(pa);

  conv1_bin<<<128 * 16, 256, 0, stream>>>(xpad, w1, b1, inv1, cc1, a1p);

  // conv2: 32x32x32 MFMA, 2-stage 36 KB LDS (R18-exact). 4096 blocks.
  bconv2_32<<<4096, 256, 0, stream>>>(a1p, bf2x, thr2, flp2, a2p);

  // conv3: 128ch->128ch, 64->32, s2. 32x32x32, dbuf LDS. 1024 blocks.
  bconv34_32<128, 2, 64, 1><<<1024, 256, 0, stream>>>(
      a2p, bf3, thr3, flp3, a3p);

  // conv4: 128ch->192ch, 32x32, s1. 32x32x32, dbuf LDS. 1024 blocks.
  bconv34_32<192, 1, 32, 0><<<1024, 256, 0, stream>>>(
      a3p, bf4, thr4, flp4, a4p);

  bconv5_pool<<<128 * NCH5, 192, 0, stream>>>(a4p, wp5, wz5, flags + 3, inv5, cc5, partial);

  head2<<<128, 192, 0, stream>>>(partial, w6, b6, fcw, fcb, out);
}